// Round 10
// baseline (530.845 us; speedup 1.0000x reference)
//
#include <hip/hip_runtime.h>

typedef short bf16x8 __attribute__((ext_vector_type(8)));
typedef float f32x4 __attribute__((ext_vector_type(4)));
typedef int   i32x4 __attribute__((ext_vector_type(4)));

#define NBLK 512   // scatter/count blocks (fixed for deterministic two-level offsets)
#define NSTAT 512  // stats partial blocks

// ---------- bf16 helpers ----------
__device__ __forceinline__ unsigned short f2bf(float f) {
    unsigned u = __float_as_uint(f);
    u += 0x7fffu + ((u >> 16) & 1u);   // round-to-nearest-even
    return (unsigned short)(u >> 16);
}
__device__ __forceinline__ float bflo(unsigned u) { return __uint_as_float(u << 16); }
__device__ __forceinline__ float bfhi(unsigned u) { return __uint_as_float(u & 0xffff0000u); }

// =================== K1: W prep + zero pooled/gcnt/counters/total ===================
__global__ __launch_bounds__(256) void k_wprep(const float* __restrict__ W0,
                                               const float* __restrict__ W1,
                                               unsigned short* __restrict__ W0t,
                                               unsigned short* __restrict__ W1t,
                                               float* __restrict__ pooled,
                                               int* __restrict__ gcnt,
                                               int* __restrict__ cnt,
                                               int* __restrict__ total) {
    int tt = blockIdx.x * 256 + threadIdx.x;   // 4096 = 2 * 32 frags * 64 lanes
    pooled[tt] = 0.f;
    pooled[tt + 4096] = 0.f;
    if (tt < 64) gcnt[tt] = 0;
    if (tt < 4) cnt[tt] = 0;
    if (tt < 512) total[tt] = 0;
    const float* W = (tt < 2048) ? W0 : W1;
    unsigned short* Wt = (tt < 2048) ? W0t : W1t;
    int t = tt & 2047;
    int f = t >> 6, lane = t & 63;
    int kc = f >> 3, nt = f & 7;
    int kbase = kc * 32 + (lane >> 4) * 8;
    int n = nt * 16 + (lane & 15);
    unsigned short t8[8];
#pragma unroll
    for (int j = 0; j < 8; ++j) t8[j] = f2bf(W[(size_t)(kbase + j) * 128 + n]);
    unsigned short* o = &Wt[(size_t)t * 8];
    *(ushort4*)&o[0] = *(ushort4*)&t8[0];
    *(ushort4*)&o[4] = *(ushort4*)&t8[4];
}

// =================== K2: per-block bucket histogram ===================
__global__ __launch_bounds__(256) void kb_count(const int* __restrict__ dst, int E, int nb,
                                                int chunk, int* __restrict__ counts) {
    __shared__ int h[512];
    for (int i = threadIdx.x; i < 512; i += 256) h[i] = 0;
    __syncthreads();
    int e0 = blockIdx.x * chunk, e1 = min(e0 + chunk, E);
    for (int e = e0 + threadIdx.x; e < e1; e += 256) atomicAdd(&h[dst[e] >> 8], 1);
    __syncthreads();
    for (int b = threadIdx.x; b < nb; b += 256) counts[b * NBLK + blockIdx.x] = h[b];
}

// =================== K3: per-bucket exclusive scan over blocks + totals ===================
__global__ __launch_bounds__(NBLK) void kb_offsets(int* __restrict__ counts,
                                                   int* __restrict__ total) {
    __shared__ int s[NBLK];
    int b = blockIdx.x, t = threadIdx.x;
    int v = counts[b * NBLK + t];
    s[t] = v; __syncthreads();
    for (int off = 1; off < NBLK; off <<= 1) {
        int x = (t >= off) ? s[t - off] : 0;
        __syncthreads();
        s[t] += x;
        __syncthreads();
    }
    counts[b * NBLK + t] = s[t] - v;          // exclusive
    if (t == NBLK - 1) total[b] = s[t];
}

// =================== K4: fused edge scatter (blocks < NBLK) + GEMM layer 1 ===================
__global__ __launch_bounds__(256) void k_scatgemm(const int* __restrict__ src,
                                                  const int* __restrict__ dst, int E, int chunk,
                                                  const int* __restrict__ counts,
                                                  const int* __restrict__ total,
                                                  int2* __restrict__ rec,
                                                  const float* __restrict__ X,
                                                  const unsigned short* __restrict__ Wt,
                                                  unsigned short* __restrict__ Hout, int N) {
    __shared__ unsigned short smem[64 * 136];   // 17.4 KB; scatter reuses as int[1024]
    const int t = threadIdx.x;
    if (blockIdx.x < NBLK) {
        int* sS  = (int*)smem;          // [512] inclusive scan of totals
        int* cur = ((int*)smem) + 512;  // [512] cursors
        sS[t] = total[t]; sS[t + 256] = total[t + 256];
        __syncthreads();
        for (int off = 1; off < 512; off <<= 1) {
            int a  = (t >= off) ? sS[t - off] : 0;
            int b2 = (t + 256 >= off) ? sS[t + 256 - off] : 0;
            __syncthreads();
            sS[t] += a; sS[t + 256] += b2;
            __syncthreads();
        }
        int blk = blockIdx.x;
        cur[t]       = sS[t] - total[t] + counts[t * NBLK + blk];
        cur[t + 256] = sS[t + 256] - total[t + 256] + counts[(t + 256) * NBLK + blk];
        __syncthreads();
        int e0 = blk * chunk, e1 = min(e0 + chunk, E);
        for (int e = e0 + t; e < e1; e += 256) {
            int s = src[e], d = dst[e];
            int pos = atomicAdd(&cur[d >> 8], 1);
            rec[pos] = make_int2(s, d);
        }
    } else {
        const int rowBase = (blockIdx.x - NBLK) * 64;
#pragma unroll
        for (int i = 0; i < 8; ++i) {
            int f4 = t + 256 * i;
            int r = f4 >> 5; int k4 = (f4 & 31) * 4;
            int gr = rowBase + r;
            float4 v = make_float4(0.f, 0.f, 0.f, 0.f);
            if (gr < N) v = *(const float4*)&X[(size_t)gr * 128 + k4];
            ushort4 p;
            p.x = f2bf(v.x); p.y = f2bf(v.y); p.z = f2bf(v.z); p.w = f2bf(v.w);
            *(ushort4*)&smem[r * 136 + k4] = p;
        }
        __syncthreads();
        const int lane = t & 63, wave = t >> 6;
        const int m = lane & 15, q = lane >> 4;
        const int rowOff = (wave * 16 + m) * 136 + q * 8;
        f32x4 acc[8];
#pragma unroll
        for (int nt = 0; nt < 8; ++nt) acc[nt] = (f32x4){0.f, 0.f, 0.f, 0.f};
        const bf16x8* WtF = (const bf16x8*)Wt;
#pragma unroll
        for (int kc = 0; kc < 4; ++kc) {
            bf16x8 xb = *(const bf16x8*)&smem[rowOff + kc * 32];
#pragma unroll
            for (int nt = 0; nt < 8; ++nt) {
                bf16x8 wa = WtF[(kc * 8 + nt) * 64 + lane];
                acc[nt] = __builtin_amdgcn_mfma_f32_16x16x32_bf16(wa, xb, acc[nt], 0, 0, 0);
            }
        }
        int grow = rowBase + wave * 16 + m;
        if (grow < N) {
#pragma unroll
            for (int nt = 0; nt < 8; ++nt) {
                ushort4 p;
                p.x = f2bf(acc[nt][0]); p.y = f2bf(acc[nt][1]);
                p.z = f2bf(acc[nt][2]); p.w = f2bf(acc[nt][3]);
                *(ushort4*)&Hout[(size_t)grow * 128 + nt * 16 + q * 4] = p;
            }
        }
    }
}

// =================== K5: per-bucket degree (+dinv, +bucket padded sum); in-block bbase ===================
__global__ __launch_bounds__(256) void kb_deg(const int2* __restrict__ rec,
                                              const int* __restrict__ total,
                                              int* __restrict__ deg,
                                              float* __restrict__ dinv,
                                              int* __restrict__ padsum, int N) {
    __shared__ int dc[256];
    __shared__ int red[256];
    int b = blockIdx.x, t = threadIdx.x;
    red[t] = ((t < b) ? total[t] : 0) + ((t + 256 < b) ? total[t + 256] : 0);
    dc[t] = 0;
    __syncthreads();
    for (int off = 128; off > 0; off >>= 1) {
        if (t < off) red[t] += red[t + off];
        __syncthreads();
    }
    int r0 = red[0];
    int r1 = r0 + total[b];
    for (int i = r0 + t; i < r1; i += 256) atomicAdd(&dc[rec[i].y & 255], 1);
    __syncthreads();
    int gn = b * 256 + t;
    int d = dc[t];
    int pd = (gn < N) ? ((d + 7) & ~7) : 0;
    if (gn < N) {
        deg[gn] = d;
        dinv[gn] = rsqrtf((float)(d + 1));
    }
    __syncthreads();
    dc[t] = pd; __syncthreads();
    for (int off = 128; off > 0; off >>= 1) {
        if (t < off) dc[t] += dc[t + off];
        __syncthreads();
    }
    if (t == 0) padsum[b] = dc[0];
}

// =================== K6: CSR placement; in-block bbase+bucketBase reductions ===================
__global__ __launch_bounds__(256) void kb_place(const int2* __restrict__ rec,
                                                const int* __restrict__ total,
                                                const int* __restrict__ padsum,
                                                const int* __restrict__ deg,
                                                const float* __restrict__ dinv,
                                                int2* __restrict__ csr,
                                                int2* __restrict__ rowdeg, int N) {
    __shared__ int sc[256];
    __shared__ int cur[256];
    __shared__ int red[256];
    int b = blockIdx.x, t = threadIdx.x;
    red[t] = ((t < b) ? total[t]  : 0) + ((t + 256 < b) ? total[t + 256]  : 0);
    sc[t]  = ((t < b) ? padsum[t] : 0) + ((t + 256 < b) ? padsum[t + 256] : 0);
    __syncthreads();
    for (int off = 128; off > 0; off >>= 1) {
        if (t < off) { red[t] += red[t + off]; sc[t] += sc[t + off]; }
        __syncthreads();
    }
    int r0 = red[0];
    int r1 = r0 + total[b];
    int bucketBase = sc[0];
    __syncthreads();
    int gn = b * 256 + t;
    int d = (gn < N) ? deg[gn] : 0;
    int pd = (d + 7) & ~7;
    sc[t] = pd; __syncthreads();
    for (int off = 1; off < 256; off <<= 1) {
        int x = (t >= off) ? sc[t - off] : 0;
        __syncthreads();
        sc[t] += x;
        __syncthreads();
    }
    int rp = bucketBase + sc[t] - pd;
    if (gn < N) rowdeg[gn] = make_int2(rp, pd);
    cur[t] = rp;
    __syncthreads();
    for (int i = r0 + t; i < r1; i += 256) {
        int2 rc = rec[i];
        int pos = atomicAdd(&cur[rc.y & 255], 1);
        float w = dinv[rc.x] * dinv[rc.y];
        csr[pos] = make_int2(rc.x, __float_as_int(w));
    }
    __syncthreads();
    if (gn < N) {
        int end = cur[t];                       // start + deg
        int pe = rp + pd;
        for (int i = end; i < pe; ++i) csr[i] = make_int2(0, 0);  // {src=0, w=0}
    }
}

// =================== MFMA GEMM (layer 2: bf16 in, BN1+ReLU fused) ===================
__global__ __launch_bounds__(256) void k_gemm(const int4* __restrict__ X,
                                              const unsigned short* __restrict__ Wt,
                                              const float* __restrict__ scale,
                                              const float* __restrict__ shift,
                                              unsigned short* __restrict__ Hout, int N) {
    __shared__ unsigned short sX[64 * 136];
    const int tid = threadIdx.x;
    const int rowBase = blockIdx.x * 64;
#pragma unroll
    for (int i = 0; i < 4; ++i) {
        int f8 = tid + 256 * i;
        int r = f8 >> 4; int k8 = (f8 & 15) * 8;
        int gr = rowBase + r;
        int4 u = make_int4(0, 0, 0, 0);
        if (gr < N) u = X[(size_t)gr * 16 + (f8 & 15)];
        float fv[8] = { bflo(u.x), bfhi(u.x), bflo(u.y), bfhi(u.y),
                        bflo(u.z), bfhi(u.z), bflo(u.w), bfhi(u.w) };
        unsigned short t8[8];
#pragma unroll
        for (int j = 0; j < 8; ++j)
            t8[j] = f2bf(fmaxf(fmaf(fv[j], scale[k8 + j], shift[k8 + j]), 0.f));
        *(ushort4*)&sX[r * 136 + k8]     = *(ushort4*)&t8[0];
        *(ushort4*)&sX[r * 136 + k8 + 4] = *(ushort4*)&t8[4];
    }
    __syncthreads();
    const int lane = tid & 63, wave = tid >> 6;
    const int m = lane & 15, q = lane >> 4;
    const int rowOff = (wave * 16 + m) * 136 + q * 8;
    f32x4 acc[8];
#pragma unroll
    for (int nt = 0; nt < 8; ++nt) acc[nt] = (f32x4){0.f, 0.f, 0.f, 0.f};
    const bf16x8* WtF = (const bf16x8*)Wt;
#pragma unroll
    for (int kc = 0; kc < 4; ++kc) {
        bf16x8 xb = *(const bf16x8*)&sX[rowOff + kc * 32];
#pragma unroll
        for (int nt = 0; nt < 8; ++nt) {
            bf16x8 wa = WtF[(kc * 8 + nt) * 64 + lane];
            acc[nt] = __builtin_amdgcn_mfma_f32_16x16x32_bf16(wa, xb, acc[nt], 0, 0, 0);
        }
    }
    int grow = rowBase + wave * 16 + m;
    if (grow < N) {
#pragma unroll
        for (int nt = 0; nt < 8; ++nt) {
            ushort4 p;
            p.x = f2bf(acc[nt][0]); p.y = f2bf(acc[nt][1]);
            p.z = f2bf(acc[nt][2]); p.w = f2bf(acc[nt][3]);
            *(ushort4*)&Hout[(size_t)grow * 128 + nt * 16 + q * 4] = p;
        }
    }
}

// =================== aggregation: 1 node/wave, pad-8, 16-deep, NT csr/out ===================
__global__ __launch_bounds__(256) void k_agg(const unsigned short* __restrict__ H,
                                             const int2* __restrict__ rowdeg,
                                             const int2* __restrict__ csr,
                                             const float* __restrict__ dinv,
                                             const float* __restrict__ bias,
                                             unsigned* __restrict__ out, int N) {
    int wave = threadIdx.x >> 6;
    int lane = threadIdx.x & 63;
    int node = blockIdx.x * 4 + wave;
    if (node >= N) return;
    const unsigned* Hu = (const unsigned*)H;
    int2 rd = rowdeg[node];
    int start = rd.x, pd = rd.y;
    float a0 = 0.f, a1 = 0.f;
    const i32x4* cp = (const i32x4*)(csr + start);
    int j = 0;
    for (; j + 16 <= pd; j += 16) {
        i32x4 q0 = __builtin_nontemporal_load(cp + 0);
        i32x4 q1 = __builtin_nontemporal_load(cp + 1);
        i32x4 q2 = __builtin_nontemporal_load(cp + 2);
        i32x4 q3 = __builtin_nontemporal_load(cp + 3);
        i32x4 q4 = __builtin_nontemporal_load(cp + 4);
        i32x4 q5 = __builtin_nontemporal_load(cp + 5);
        i32x4 q6 = __builtin_nontemporal_load(cp + 6);
        i32x4 q7 = __builtin_nontemporal_load(cp + 7);
        cp += 8;
        unsigned u0 = Hu[(size_t)q0[0] * 64 + lane];
        unsigned u1 = Hu[(size_t)q0[2] * 64 + lane];
        unsigned u2 = Hu[(size_t)q1[0] * 64 + lane];
        unsigned u3 = Hu[(size_t)q1[2] * 64 + lane];
        unsigned u4 = Hu[(size_t)q2[0] * 64 + lane];
        unsigned u5 = Hu[(size_t)q2[2] * 64 + lane];
        unsigned u6 = Hu[(size_t)q3[0] * 64 + lane];
        unsigned u7 = Hu[(size_t)q3[2] * 64 + lane];
        unsigned u8 = Hu[(size_t)q4[0] * 64 + lane];
        unsigned u9 = Hu[(size_t)q4[2] * 64 + lane];
        unsigned uA = Hu[(size_t)q5[0] * 64 + lane];
        unsigned uB = Hu[(size_t)q5[2] * 64 + lane];
        unsigned uC = Hu[(size_t)q6[0] * 64 + lane];
        unsigned uD = Hu[(size_t)q6[2] * 64 + lane];
        unsigned uE = Hu[(size_t)q7[0] * 64 + lane];
        unsigned uF = Hu[(size_t)q7[2] * 64 + lane];
        float w0 = __int_as_float(q0[1]), w1 = __int_as_float(q0[3]);
        float w2 = __int_as_float(q1[1]), w3 = __int_as_float(q1[3]);
        float w4 = __int_as_float(q2[1]), w5 = __int_as_float(q2[3]);
        float w6 = __int_as_float(q3[1]), w7 = __int_as_float(q3[3]);
        float w8 = __int_as_float(q4[1]), w9 = __int_as_float(q4[3]);
        float wA = __int_as_float(q5[1]), wB = __int_as_float(q5[3]);
        float wC = __int_as_float(q6[1]), wD = __int_as_float(q6[3]);
        float wE = __int_as_float(q7[1]), wF = __int_as_float(q7[3]);
        a0 = fmaf(w0, bflo(u0), a0); a1 = fmaf(w0, bfhi(u0), a1);
        a0 = fmaf(w1, bflo(u1), a0); a1 = fmaf(w1, bfhi(u1), a1);
        a0 = fmaf(w2, bflo(u2), a0); a1 = fmaf(w2, bfhi(u2), a1);
        a0 = fmaf(w3, bflo(u3), a0); a1 = fmaf(w3, bfhi(u3), a1);
        a0 = fmaf(w4, bflo(u4), a0); a1 = fmaf(w4, bfhi(u4), a1);
        a0 = fmaf(w5, bflo(u5), a0); a1 = fmaf(w5, bfhi(u5), a1);
        a0 = fmaf(w6, bflo(u6), a0); a1 = fmaf(w6, bfhi(u6), a1);
        a0 = fmaf(w7, bflo(u7), a0); a1 = fmaf(w7, bfhi(u7), a1);
        a0 = fmaf(w8, bflo(u8), a0); a1 = fmaf(w8, bfhi(u8), a1);
        a0 = fmaf(w9, bflo(u9), a0); a1 = fmaf(w9, bfhi(u9), a1);
        a0 = fmaf(wA, bflo(uA), a0); a1 = fmaf(wA, bfhi(uA), a1);
        a0 = fmaf(wB, bflo(uB), a0); a1 = fmaf(wB, bfhi(uB), a1);
        a0 = fmaf(wC, bflo(uC), a0); a1 = fmaf(wC, bfhi(uC), a1);
        a0 = fmaf(wD, bflo(uD), a0); a1 = fmaf(wD, bfhi(uD), a1);
        a0 = fmaf(wE, bflo(uE), a0); a1 = fmaf(wE, bfhi(uE), a1);
        a0 = fmaf(wF, bflo(uF), a0); a1 = fmaf(wF, bfhi(uF), a1);
    }
    if (j < pd) {   // remaining group of 8
        i32x4 q0 = __builtin_nontemporal_load(cp + 0);
        i32x4 q1 = __builtin_nontemporal_load(cp + 1);
        i32x4 q2 = __builtin_nontemporal_load(cp + 2);
        i32x4 q3 = __builtin_nontemporal_load(cp + 3);
        unsigned u0 = Hu[(size_t)q0[0] * 64 + lane];
        unsigned u1 = Hu[(size_t)q0[2] * 64 + lane];
        unsigned u2 = Hu[(size_t)q1[0] * 64 + lane];
        unsigned u3 = Hu[(size_t)q1[2] * 64 + lane];
        unsigned u4 = Hu[(size_t)q2[0] * 64 + lane];
        unsigned u5 = Hu[(size_t)q2[2] * 64 + lane];
        unsigned u6 = Hu[(size_t)q3[0] * 64 + lane];
        unsigned u7 = Hu[(size_t)q3[2] * 64 + lane];
        float w0 = __int_as_float(q0[1]), w1 = __int_as_float(q0[3]);
        float w2 = __int_as_float(q1[1]), w3 = __int_as_float(q1[3]);
        float w4 = __int_as_float(q2[1]), w5 = __int_as_float(q2[3]);
        float w6 = __int_as_float(q3[1]), w7 = __int_as_float(q3[3]);
        a0 = fmaf(w0, bflo(u0), a0); a1 = fmaf(w0, bfhi(u0), a1);
        a0 = fmaf(w1, bflo(u1), a0); a1 = fmaf(w1, bfhi(u1), a1);
        a0 = fmaf(w2, bflo(u2), a0); a1 = fmaf(w2, bfhi(u2), a1);
        a0 = fmaf(w3, bflo(u3), a0); a1 = fmaf(w3, bfhi(u3), a1);
        a0 = fmaf(w4, bflo(u4), a0); a1 = fmaf(w4, bfhi(u4), a1);
        a0 = fmaf(w5, bflo(u5), a0); a1 = fmaf(w5, bfhi(u5), a1);
        a0 = fmaf(w6, bflo(u6), a0); a1 = fmaf(w6, bfhi(u6), a1);
        a0 = fmaf(w7, bflo(u7), a0); a1 = fmaf(w7, bfhi(u7), a1);
    }
    { // self loop
        float dn = dinv[node];
        float w = dn * dn;
        unsigned u = Hu[(size_t)node * 64 + lane];
        a0 = fmaf(w, bflo(u), a0);
        a1 = fmaf(w, bfhi(u), a1);
    }
    float2 bv = ((const float2*)bias)[lane];
    a0 += bv.x; a1 += bv.y;
    unsigned pk = (unsigned)f2bf(a0) | ((unsigned)f2bf(a1) << 16);
    __builtin_nontemporal_store(pk, &out[(size_t)node * 64 + lane]);
}

// =================== BN stats + fused finalize (last-block ticket) ===================
__global__ __launch_bounds__(256) void k_stats(const int4* __restrict__ B4, int N,
                                               float* __restrict__ P1,
                                               float* __restrict__ P2,
                                               const float* __restrict__ g,
                                               const float* __restrict__ be,
                                               float* __restrict__ scale,
                                               float* __restrict__ shift,
                                               float invN, int* __restrict__ counter) {
    int tid = threadIdx.x;
    int lane = tid & 63, wave = tid >> 6;
    int c = lane & 15;
    int rsub = lane >> 4;
    float s1[8] = {0.f,0.f,0.f,0.f,0.f,0.f,0.f,0.f};
    float s2[8] = {0.f,0.f,0.f,0.f,0.f,0.f,0.f,0.f};
    for (int r = blockIdx.x * 16 + wave * 4 + rsub; r < N; r += NSTAT * 16) {
        int4 u = B4[(size_t)r * 16 + c];
        float f[8] = { bflo(u.x), bfhi(u.x), bflo(u.y), bfhi(u.y),
                       bflo(u.z), bfhi(u.z), bflo(u.w), bfhi(u.w) };
#pragma unroll
        for (int j = 0; j < 8; ++j) { s1[j] += f[j]; s2[j] = fmaf(f[j], f[j], s2[j]); }
    }
#pragma unroll
    for (int j = 0; j < 8; ++j) {
        s1[j] += __shfl_xor(s1[j], 16, 64);
        s1[j] += __shfl_xor(s1[j], 32, 64);
        s2[j] += __shfl_xor(s2[j], 16, 64);
        s2[j] += __shfl_xor(s2[j], 32, 64);
    }
    __shared__ float ls1[4][128], ls2[4][128];
    if (rsub == 0) {
#pragma unroll
        for (int j = 0; j < 8; ++j) { ls1[wave][c * 8 + j] = s1[j]; ls2[wave][c * 8 + j] = s2[j]; }
    }
    __syncthreads();
    if (tid < 128) {
        P1[blockIdx.x * 128 + tid] = ls1[0][tid] + ls1[1][tid] + ls1[2][tid] + ls1[3][tid];
        P2[blockIdx.x * 128 + tid] = ls2[0][tid] + ls2[1][tid] + ls2[2][tid] + ls2[3][tid];
    }
    // last-block finalize
    __threadfence();
    __shared__ int isLast;
    if (tid == 0) isLast = (atomicAdd(counter, 1) == (int)gridDim.x - 1);
    __syncthreads();
    if (!isLast) return;
    __threadfence();
    int f = tid & 127;
    const float* P = (tid < 128) ? P1 : P2;
    float s = 0.f;
#pragma unroll 8
    for (int i = 0; i < NSTAT; ++i) s += P[i * 128 + f];
    __shared__ float sm[256];
    sm[tid] = s;
    __syncthreads();
    if (tid < 128) {
        float mu = sm[tid] * invN;
        float var = sm[tid + 128] * invN - mu * mu;
        float sc = g[tid] * rsqrtf(var + 1e-5f);
        scale[tid] = sc;
        shift[tid] = fmaf(-mu, sc, be[tid]);
    }
}

// =================== pool (BN2+ReLU+count, LDS-staged) + fused FC (last-block) ===================
__global__ __launch_bounds__(256) void k_pool(const int4* __restrict__ B4,
                                              const float* __restrict__ scale,
                                              const float* __restrict__ shift,
                                              const int* __restrict__ batch, int N,
                                              int rpb, float* __restrict__ pooled,
                                              int* __restrict__ gcnt,
                                              const float* __restrict__ Wfc,
                                              const float* __restrict__ bfc,
                                              float* __restrict__ out,
                                              int* __restrict__ counter) {
    __shared__ float lp[64 * 128];
    __shared__ int lc[64];
    int tid = threadIdx.x;
    int r0 = blockIdx.x * rpb;
    int r1 = min(r0 + rpb, N);
    int g0 = batch[r0];
    int g1 = batch[r1 - 1];
    for (int i = g0 * 128 + tid; i < (g1 + 1) * 128; i += 256) lp[i] = 0.f;
    if (tid <= g1 - g0) lc[g0 + tid] = 0;
    __syncthreads();

    int c = tid & 15;
    int rh = tid >> 4;
    float sc[8], sh[8];
#pragma unroll
    for (int j = 0; j < 8; ++j) { sc[j] = scale[c * 8 + j]; sh[j] = shift[c * 8 + j]; }
    float acc[8] = {0.f,0.f,0.f,0.f,0.f,0.f,0.f,0.f};
    int cnt = 0;
    int cur = -1;
    for (int r = r0 + rh; r < r1; r += 16) {
        int g = batch[r];
        if (g != cur) {
            if (cur >= 0) {
#pragma unroll
                for (int j = 0; j < 8; ++j)
                    atomicAdd(&lp[cur * 128 + c * 8 + j], acc[j]);
                if (c == 0) atomicAdd(&lc[cur], cnt);
            }
#pragma unroll
            for (int j = 0; j < 8; ++j) acc[j] = 0.f;
            cnt = 0;
            cur = g;
        }
        int4 u = B4[(size_t)r * 16 + c];
        float f[8] = { bflo(u.x), bfhi(u.x), bflo(u.y), bfhi(u.y),
                       bflo(u.z), bfhi(u.z), bflo(u.w), bfhi(u.w) };
#pragma unroll
        for (int j = 0; j < 8; ++j) acc[j] += fmaxf(fmaf(f[j], sc[j], sh[j]), 0.f);
        ++cnt;
    }
    if (cur >= 0) {
#pragma unroll
        for (int j = 0; j < 8; ++j)
            atomicAdd(&lp[cur * 128 + c * 8 + j], acc[j]);
        if (c == 0) atomicAdd(&lc[cur], cnt);
    }
    __syncthreads();
    for (int i = g0 * 128 + tid; i < (g1 + 1) * 128; i += 256) {
        float v = lp[i];
        if (v != 0.f) atomicAdd(&pooled[i], v);
    }
    if (tid <= g1 - g0) {
        int v = lc[g0 + tid];
        if (v) atomicAdd(&gcnt[g0 + tid], v);
    }
    // last-block FC
    __threadfence();
    __shared__ int isLast;
    if (tid == 0) isLast = (atomicAdd(counter, 1) == (int)gridDim.x - 1);
    __syncthreads();
    if (!isLast) return;
    __threadfence();
    for (int idx = tid; idx < 64 * 32; idx += 256) {
        int g = idx >> 5, o = idx & 31;
        float inv = 1.f / fmaxf((float)gcnt[g], 1.f);
        float a = bfc[o];
        for (int k = 0; k < 128; ++k)
            a = fmaf(pooled[g * 128 + k] * inv, Wfc[k * 32 + o], a);
        out[idx] = a;
    }
}

extern "C" void kernel_launch(void* const* d_in, const int* in_sizes, int n_in,
                              void* d_out, int out_size, void* d_ws, size_t ws_size,
                              hipStream_t stream) {
    const float* x    = (const float*)d_in[0];
    const int*  eidx  = (const int*)d_in[1];
    const int*  batch = (const int*)d_in[2];
    const float* W0 = (const float*)d_in[3];
    const float* b0 = (const float*)d_in[4];
    const float* g0 = (const float*)d_in[5];
    const float* be0 = (const float*)d_in[6];
    const float* W1 = (const float*)d_in[7];
    const float* b1 = (const float*)d_in[8];
    const float* g1 = (const float*)d_in[9];
    const float* be1 = (const float*)d_in[10];
    const float* Wfc = (const float*)d_in[11];
    const float* bfc = (const float*)d_in[12];
    float* out = (float*)d_out;

    const int N = in_sizes[0] / 128;
    const int E = in_sizes[1] / 2;
    const int* esrc = eidx;
    const int* edst = eidx + E;
    const int NB = (N + 255) >> 8;               // buckets of 256 nodes (<=512)
    const size_t paddedE = (size_t)E + 7 * (size_t)N;

    // ---- workspace carve-up ----
    char* base = (char*)d_ws;
    size_t off = 0;
    auto take = [&](size_t bytes) -> char* {
        char* p = base + off;
        off = (off + bytes + 255) & ~(size_t)255;
        return p;
    };
    unsigned short* hA = (unsigned short*)take((size_t)N * 128 * 2); // bf16 h buffer
    unsigned* B = (unsigned*)take((size_t)N * 64 * 4);               // bf16-packed agg buffer
    int2* rec = (int2*)B;                                            // bucket records alias B (dead before agg1)
    int2* csr   = (int2*)take(paddedE * 8);
    int2* rowdeg = (int2*)take((size_t)N * 8);
    int* deg    = (int*)take((size_t)N * 4);
    float* dinv = (float*)take((size_t)N * 4);
    int* counts = (int*)take((size_t)512 * NBLK * 4);                // 1 MB
    int* total  = (int*)take(512 * 4);
    int* padsum = (int*)take(512 * 4);
    int* cntrs  = (int*)take(4 * 4);
    unsigned short* W0t = (unsigned short*)take(16384 * 2);
    unsigned short* W1t = (unsigned short*)take(16384 * 2);
    float* P1 = (float*)take((size_t)NSTAT * 128 * 4);
    float* P2 = (float*)take((size_t)NSTAT * 128 * 4);
    float* pooled = (float*)take(64 * 128 * 4);
    int*   gcnt   = (int*)take(64 * 4);
    float* scale1 = (float*)take(128 * 4);
    float* shift1 = (float*)take(128 * 4);
    float* scale2 = (float*)take(128 * 4);
    float* shift2 = (float*)take(128 * 4);
    (void)ws_size; (void)n_in; (void)out_size;

    const int gGemm = (N + 63) / 64;
    const int gAgg  = (N + 3) / 4;
    const float invN = 1.0f / (float)N;
    const int CH = (E + NBLK - 1) / NBLK;

    // K1: weight prep + zero pooled/gcnt/counters/total
    k_wprep<<<16, 256, 0, stream>>>(W0, W1, W0t, W1t, pooled, gcnt, cntrs, total);
    // K2-K3: bucket histogram + offsets
    kb_count<<<NBLK, 256, 0, stream>>>(edst, E, NB, CH, counts);
    kb_offsets<<<NB, NBLK, 0, stream>>>(counts, total);
    // K4: fused edge scatter + GEMM layer 1 (independent)
    k_scatgemm<<<NBLK + gGemm, 256, 0, stream>>>(esrc, edst, E, CH, counts, total,
                                                 rec, x, W0t, hA, N);
    // K5-K6: degrees + CSR placement (in-block scans; no kb_base launches)
    kb_deg<<<NB, 256, 0, stream>>>(rec, total, deg, dinv, padsum, N);
    kb_place<<<NB, 256, 0, stream>>>(rec, total, padsum, deg, dinv, csr, rowdeg, N);

    // layer 1 aggregate + stats(+final)
    k_agg<<<gAgg, 256, 0, stream>>>(hA, rowdeg, csr, dinv, b0, B, N);
    k_stats<<<NSTAT, 256, 0, stream>>>((const int4*)B, N, P1, P2, g0, be0,
                                       scale1, shift1, invN, cntrs + 0);
    // layer 2
    k_gemm<<<gGemm, 256, 0, stream>>>((const int4*)B, W1t, scale1, shift1, hA, N);
    k_agg<<<gAgg, 256, 0, stream>>>(hA, rowdeg, csr, dinv, b1, B, N);
    k_stats<<<NSTAT, 256, 0, stream>>>((const int4*)B, N, P1, P2, g1, be1,
                                       scale2, shift2, invN, cntrs + 1);
    // pool(+fc)
    const int rpb = (N + 511) / 512;
    k_pool<<<(N + rpb - 1) / rpb, 256, 0, stream>>>((const int4*)B, scale2, shift2,
                                                    batch, N, rpb, pooled, gcnt,
                                                    Wfc, bfc, out, cntrs + 2);
}

// Round 11
// 391.529 us; speedup vs baseline: 1.3558x; 1.3558x over previous
//
#include <hip/hip_runtime.h>

typedef short bf16x8 __attribute__((ext_vector_type(8)));
typedef float f32x4 __attribute__((ext_vector_type(4)));

#define NBLK 512   // scatter blocks (fixed for deterministic two-level offsets)
#define NSTAT 512  // stats partial blocks

// ---------- bf16 helpers ----------
__device__ __forceinline__ unsigned short f2bf(float f) {
    unsigned u = __float_as_uint(f);
    u += 0x7fffu + ((u >> 16) & 1u);   // round-to-nearest-even
    return (unsigned short)(u >> 16);
}
__device__ __forceinline__ float bflo(unsigned u) { return __uint_as_float(u << 16); }
__device__ __forceinline__ float bfhi(unsigned u) { return __uint_as_float(u & 0xffff0000u); }

// =================== bucketed CSR build (bucket = dst>>8; zero global atomics) ===================

__global__ __launch_bounds__(256) void kb_count(const int* __restrict__ dst, int E, int nb,
                                                int chunk, int* __restrict__ counts) {
    __shared__ int h[512];
    for (int i = threadIdx.x; i < 512; i += 256) h[i] = 0;
    __syncthreads();
    int e0 = blockIdx.x * chunk, e1 = min(e0 + chunk, E);
    for (int e = e0 + threadIdx.x; e < e1; e += 256) atomicAdd(&h[dst[e] >> 8], 1);
    __syncthreads();
    for (int b = threadIdx.x; b < nb; b += 256) counts[b * NBLK + blockIdx.x] = h[b];
}

__global__ __launch_bounds__(NBLK) void kb_offsets(int* __restrict__ counts,
                                                   int* __restrict__ total) {
    __shared__ int s[NBLK];
    int b = blockIdx.x, t = threadIdx.x;
    int v = counts[b * NBLK + t];
    s[t] = v; __syncthreads();
    for (int off = 1; off < NBLK; off <<= 1) {
        int x = (t >= off) ? s[t - off] : 0;
        __syncthreads();
        s[t] += x;
        __syncthreads();
    }
    counts[b * NBLK + t] = s[t] - v;          // exclusive
    if (t == NBLK - 1) total[b] = s[t];
}

// generic 512-entry exclusive scan (bucket totals AND bucket pad-sums)
__global__ __launch_bounds__(512) void kb_base(const int* __restrict__ in, int nb,
                                               int* __restrict__ outb) {
    __shared__ int s[512];
    int t = threadIdx.x;
    int v = (t < nb) ? in[t] : 0;
    s[t] = v; __syncthreads();
    for (int off = 1; off < 512; off <<= 1) {
        int x = (t >= off) ? s[t - off] : 0;
        __syncthreads();
        s[t] += x;
        __syncthreads();
    }
    if (t < nb) outb[t] = s[t] - v;
}

__global__ __launch_bounds__(NBLK) void kb_scatter(const int* __restrict__ src,
                                                   const int* __restrict__ dst, int E, int nb,
                                                   int chunk,
                                                   const int* __restrict__ counts,
                                                   const int* __restrict__ bbase,
                                                   int2* __restrict__ rec) {
    __shared__ int cur[512];
    int t = threadIdx.x;
    if (t < nb) cur[t] = bbase[t] + counts[t * NBLK + blockIdx.x];
    __syncthreads();
    int e0 = blockIdx.x * chunk, e1 = min(e0 + chunk, E);
    for (int e = e0 + t; e < e1; e += NBLK) {
        int s = src[e], d = dst[e];
        int pos = atomicAdd(&cur[d >> 8], 1);
        rec[pos] = make_int2(s, d);
    }
}

// per-bucket degree count via LDS (+ fused dinv, + bucket padded-deg sum)
__global__ __launch_bounds__(256) void kb_deg(const int2* __restrict__ rec,
                                              const int* __restrict__ bbase,
                                              const int* __restrict__ total,
                                              int* __restrict__ deg,
                                              float* __restrict__ dinv,
                                              int* __restrict__ padsum, int N) {
    __shared__ int dc[256];
    int b = blockIdx.x, t = threadIdx.x;
    dc[t] = 0; __syncthreads();
    int r0 = bbase[b], r1 = r0 + total[b];
    for (int i = r0 + t; i < r1; i += 256) atomicAdd(&dc[rec[i].y & 255], 1);
    __syncthreads();
    int gn = b * 256 + t;
    int d = dc[t];
    int pd = (gn < N) ? ((d + 7) & ~7) : 0;
    if (gn < N) {
        deg[gn] = d;
        dinv[gn] = rsqrtf((float)(d + 1));
    }
    __syncthreads();
    dc[t] = pd; __syncthreads();
    for (int off = 128; off > 0; off >>= 1) {
        if (t < off) dc[t] += dc[t + off];
        __syncthreads();
    }
    if (t == 0) padsum[b] = dc[0];
}

// per-bucket CSR placement: intra-bucket scan -> rowdeg{start,pd}, LDS cursors, pad writes
__global__ __launch_bounds__(256) void kb_place(const int2* __restrict__ rec,
                                                const int* __restrict__ bbase,
                                                const int* __restrict__ total,
                                                const int* __restrict__ bucketBase,
                                                const int* __restrict__ deg,
                                                const float* __restrict__ dinv,
                                                int2* __restrict__ csr,
                                                int2* __restrict__ rowdeg, int N) {
    __shared__ int sc[256];
    __shared__ int cur[256];
    int b = blockIdx.x, t = threadIdx.x;
    int gn = b * 256 + t;
    int d = (gn < N) ? deg[gn] : 0;
    int pd = (d + 7) & ~7;
    sc[t] = pd; __syncthreads();
    for (int off = 1; off < 256; off <<= 1) {
        int x = (t >= off) ? sc[t - off] : 0;
        __syncthreads();
        sc[t] += x;
        __syncthreads();
    }
    int rp = bucketBase[b] + sc[t] - pd;
    if (gn < N) rowdeg[gn] = make_int2(rp, pd);
    cur[t] = rp;
    __syncthreads();
    int r0 = bbase[b], r1 = r0 + total[b];
    for (int i = r0 + t; i < r1; i += 256) {
        int2 rc = rec[i];
        int pos = atomicAdd(&cur[rc.y & 255], 1);
        float w = dinv[rc.x] * dinv[rc.y];
        csr[pos] = make_int2(rc.x, __float_as_int(w));
    }
    __syncthreads();
    if (gn < N) {
        int end = cur[t];                       // start + deg
        int pe = rp + pd;
        for (int i = end; i < pe; ++i) csr[i] = make_int2(0, 0);  // {src=0, w=0}
    }
}

// =================== W prep (both weights) + zero pooled/gcnt ===================
__global__ __launch_bounds__(256) void k_wprep(const float* __restrict__ W0,
                                               const float* __restrict__ W1,
                                               unsigned short* __restrict__ W0t,
                                               unsigned short* __restrict__ W1t,
                                               float* __restrict__ pooled,
                                               int* __restrict__ gcnt) {
    int tt = blockIdx.x * 256 + threadIdx.x;   // 4096 = 2 * 32 frags * 64 lanes
    pooled[tt] = 0.f;
    pooled[tt + 4096] = 0.f;
    if (tt < 64) gcnt[tt] = 0;
    const float* W = (tt < 2048) ? W0 : W1;
    unsigned short* Wt = (tt < 2048) ? W0t : W1t;
    int t = tt & 2047;
    int f = t >> 6, lane = t & 63;
    int kc = f >> 3, nt = f & 7;
    int kbase = kc * 32 + (lane >> 4) * 8;
    int n = nt * 16 + (lane & 15);
    unsigned short t8[8];
#pragma unroll
    for (int j = 0; j < 8; ++j) t8[j] = f2bf(W[(size_t)(kbase + j) * 128 + n]);
    unsigned short* o = &Wt[(size_t)t * 8];
    *(ushort4*)&o[0] = *(ushort4*)&t8[0];
    *(ushort4*)&o[4] = *(ushort4*)&t8[4];
}

// =================== MFMA GEMM: Hout(bf16) = act(X) @ W ===================
__global__ __launch_bounds__(256) void k_gemm(const void* __restrict__ Xv,
                                              const unsigned short* __restrict__ Wt,
                                              const float* __restrict__ scale,
                                              const float* __restrict__ shift,
                                              unsigned short* __restrict__ Hout,
                                              int N, int xbf16) {
    __shared__ unsigned short sX[64 * 136];
    const int tid = threadIdx.x;
    const int rowBase = blockIdx.x * 64;

    if (!xbf16) {
        const float* X = (const float*)Xv;
#pragma unroll
        for (int i = 0; i < 8; ++i) {
            int f4 = tid + 256 * i;
            int r = f4 >> 5; int k4 = (f4 & 31) * 4;
            int gr = rowBase + r;
            float4 v = make_float4(0.f, 0.f, 0.f, 0.f);
            if (gr < N) v = *(const float4*)&X[(size_t)gr * 128 + k4];
            ushort4 p;
            p.x = f2bf(v.x); p.y = f2bf(v.y); p.z = f2bf(v.z); p.w = f2bf(v.w);
            *(ushort4*)&sX[r * 136 + k4] = p;
        }
    } else {
        const int4* X = (const int4*)Xv;
#pragma unroll
        for (int i = 0; i < 4; ++i) {
            int f8 = tid + 256 * i;
            int r = f8 >> 4; int k8 = (f8 & 15) * 8;
            int gr = rowBase + r;
            int4 u = make_int4(0, 0, 0, 0);
            if (gr < N) u = X[(size_t)gr * 16 + (f8 & 15)];
            float fv[8] = { bflo(u.x), bfhi(u.x), bflo(u.y), bfhi(u.y),
                            bflo(u.z), bfhi(u.z), bflo(u.w), bfhi(u.w) };
            unsigned short t8[8];
#pragma unroll
            for (int j = 0; j < 8; ++j)
                t8[j] = f2bf(fmaxf(fmaf(fv[j], scale[k8 + j], shift[k8 + j]), 0.f));
            *(ushort4*)&sX[r * 136 + k8]     = *(ushort4*)&t8[0];
            *(ushort4*)&sX[r * 136 + k8 + 4] = *(ushort4*)&t8[4];
        }
    }
    __syncthreads();

    const int lane = tid & 63, wave = tid >> 6;
    const int m = lane & 15, q = lane >> 4;
    const int rowOff = (wave * 16 + m) * 136 + q * 8;
    f32x4 acc[8];
#pragma unroll
    for (int nt = 0; nt < 8; ++nt) acc[nt] = (f32x4){0.f, 0.f, 0.f, 0.f};
    const bf16x8* WtF = (const bf16x8*)Wt;
#pragma unroll
    for (int kc = 0; kc < 4; ++kc) {
        bf16x8 xb = *(const bf16x8*)&sX[rowOff + kc * 32];
#pragma unroll
        for (int nt = 0; nt < 8; ++nt) {
            bf16x8 wa = WtF[(kc * 8 + nt) * 64 + lane];
            acc[nt] = __builtin_amdgcn_mfma_f32_16x16x32_bf16(wa, xb, acc[nt], 0, 0, 0);
        }
    }
    int grow = rowBase + wave * 16 + m;
    if (grow < N) {
#pragma unroll
        for (int nt = 0; nt < 8; ++nt) {
            ushort4 p;
            p.x = f2bf(acc[nt][0]); p.y = f2bf(acc[nt][1]);
            p.z = f2bf(acc[nt][2]); p.w = f2bf(acc[nt][3]);
            *(ushort4*)&Hout[(size_t)grow * 128 + nt * 16 + q * 4] = p;
        }
    }
}

// =================== aggregation: 1 node/wave, pad-8, 16-deep unroll ===================
__global__ __launch_bounds__(256) void k_agg(const unsigned short* __restrict__ H,
                                             const int2* __restrict__ rowdeg,
                                             const int2* __restrict__ csr,
                                             const float* __restrict__ dinv,
                                             const float* __restrict__ bias,
                                             unsigned* __restrict__ out, int N) {
    int wave = threadIdx.x >> 6;
    int lane = threadIdx.x & 63;
    int node = blockIdx.x * 4 + wave;
    if (node >= N) return;
    const unsigned* Hu = (const unsigned*)H;
    int2 rd = rowdeg[node];
    int start = rd.x, pd = rd.y;
    float a0 = 0.f, a1 = 0.f;
    const int4* cp = (const int4*)(csr + start);
    int j = 0;
    for (; j + 16 <= pd; j += 16) {
        int4 q0 = cp[0], q1 = cp[1], q2 = cp[2], q3 = cp[3];
        int4 q4 = cp[4], q5 = cp[5], q6 = cp[6], q7 = cp[7];
        cp += 8;
        unsigned u0 = Hu[(size_t)q0.x * 64 + lane];
        unsigned u1 = Hu[(size_t)q0.z * 64 + lane];
        unsigned u2 = Hu[(size_t)q1.x * 64 + lane];
        unsigned u3 = Hu[(size_t)q1.z * 64 + lane];
        unsigned u4 = Hu[(size_t)q2.x * 64 + lane];
        unsigned u5 = Hu[(size_t)q2.z * 64 + lane];
        unsigned u6 = Hu[(size_t)q3.x * 64 + lane];
        unsigned u7 = Hu[(size_t)q3.z * 64 + lane];
        unsigned u8 = Hu[(size_t)q4.x * 64 + lane];
        unsigned u9 = Hu[(size_t)q4.z * 64 + lane];
        unsigned uA = Hu[(size_t)q5.x * 64 + lane];
        unsigned uB = Hu[(size_t)q5.z * 64 + lane];
        unsigned uC = Hu[(size_t)q6.x * 64 + lane];
        unsigned uD = Hu[(size_t)q6.z * 64 + lane];
        unsigned uE = Hu[(size_t)q7.x * 64 + lane];
        unsigned uF = Hu[(size_t)q7.z * 64 + lane];
        float w0 = __int_as_float(q0.y), w1 = __int_as_float(q0.w);
        float w2 = __int_as_float(q1.y), w3 = __int_as_float(q1.w);
        float w4 = __int_as_float(q2.y), w5 = __int_as_float(q2.w);
        float w6 = __int_as_float(q3.y), w7 = __int_as_float(q3.w);
        float w8 = __int_as_float(q4.y), w9 = __int_as_float(q4.w);
        float wA = __int_as_float(q5.y), wB = __int_as_float(q5.w);
        float wC = __int_as_float(q6.y), wD = __int_as_float(q6.w);
        float wE = __int_as_float(q7.y), wF = __int_as_float(q7.w);
        a0 = fmaf(w0, bflo(u0), a0); a1 = fmaf(w0, bfhi(u0), a1);
        a0 = fmaf(w1, bflo(u1), a0); a1 = fmaf(w1, bfhi(u1), a1);
        a0 = fmaf(w2, bflo(u2), a0); a1 = fmaf(w2, bfhi(u2), a1);
        a0 = fmaf(w3, bflo(u3), a0); a1 = fmaf(w3, bfhi(u3), a1);
        a0 = fmaf(w4, bflo(u4), a0); a1 = fmaf(w4, bfhi(u4), a1);
        a0 = fmaf(w5, bflo(u5), a0); a1 = fmaf(w5, bfhi(u5), a1);
        a0 = fmaf(w6, bflo(u6), a0); a1 = fmaf(w6, bfhi(u6), a1);
        a0 = fmaf(w7, bflo(u7), a0); a1 = fmaf(w7, bfhi(u7), a1);
        a0 = fmaf(w8, bflo(u8), a0); a1 = fmaf(w8, bfhi(u8), a1);
        a0 = fmaf(w9, bflo(u9), a0); a1 = fmaf(w9, bfhi(u9), a1);
        a0 = fmaf(wA, bflo(uA), a0); a1 = fmaf(wA, bfhi(uA), a1);
        a0 = fmaf(wB, bflo(uB), a0); a1 = fmaf(wB, bfhi(uB), a1);
        a0 = fmaf(wC, bflo(uC), a0); a1 = fmaf(wC, bfhi(uC), a1);
        a0 = fmaf(wD, bflo(uD), a0); a1 = fmaf(wD, bfhi(uD), a1);
        a0 = fmaf(wE, bflo(uE), a0); a1 = fmaf(wE, bfhi(uE), a1);
        a0 = fmaf(wF, bflo(uF), a0); a1 = fmaf(wF, bfhi(uF), a1);
    }
    if (j < pd) {   // remaining group of 8
        int4 q0 = cp[0], q1 = cp[1], q2 = cp[2], q3 = cp[3];
        unsigned u0 = Hu[(size_t)q0.x * 64 + lane];
        unsigned u1 = Hu[(size_t)q0.z * 64 + lane];
        unsigned u2 = Hu[(size_t)q1.x * 64 + lane];
        unsigned u3 = Hu[(size_t)q1.z * 64 + lane];
        unsigned u4 = Hu[(size_t)q2.x * 64 + lane];
        unsigned u5 = Hu[(size_t)q2.z * 64 + lane];
        unsigned u6 = Hu[(size_t)q3.x * 64 + lane];
        unsigned u7 = Hu[(size_t)q3.z * 64 + lane];
        float w0 = __int_as_float(q0.y), w1 = __int_as_float(q0.w);
        float w2 = __int_as_float(q1.y), w3 = __int_as_float(q1.w);
        float w4 = __int_as_float(q2.y), w5 = __int_as_float(q2.w);
        float w6 = __int_as_float(q3.y), w7 = __int_as_float(q3.w);
        a0 = fmaf(w0, bflo(u0), a0); a1 = fmaf(w0, bfhi(u0), a1);
        a0 = fmaf(w1, bflo(u1), a0); a1 = fmaf(w1, bfhi(u1), a1);
        a0 = fmaf(w2, bflo(u2), a0); a1 = fmaf(w2, bfhi(u2), a1);
        a0 = fmaf(w3, bflo(u3), a0); a1 = fmaf(w3, bfhi(u3), a1);
        a0 = fmaf(w4, bflo(u4), a0); a1 = fmaf(w4, bfhi(u4), a1);
        a0 = fmaf(w5, bflo(u5), a0); a1 = fmaf(w5, bfhi(u5), a1);
        a0 = fmaf(w6, bflo(u6), a0); a1 = fmaf(w6, bfhi(u6), a1);
        a0 = fmaf(w7, bflo(u7), a0); a1 = fmaf(w7, bfhi(u7), a1);
    }
    { // self loop
        float dn = dinv[node];
        float w = dn * dn;
        unsigned u = Hu[(size_t)node * 64 + lane];
        a0 = fmaf(w, bflo(u), a0);
        a1 = fmaf(w, bfhi(u), a1);
    }
    float2 bv = ((const float2*)bias)[lane];
    a0 += bv.x; a1 += bv.y;
    out[(size_t)node * 64 + lane] = (unsigned)f2bf(a0) | ((unsigned)f2bf(a1) << 16);
}

// ---------- BN column stats: int4 loads, shuffle-reduce, per-block partials ----------
__global__ __launch_bounds__(256) void k_stats(const int4* __restrict__ B4, int N,
                                               float* __restrict__ P1,
                                               float* __restrict__ P2) {
    int tid = threadIdx.x;
    int lane = tid & 63, wave = tid >> 6;
    int c = lane & 15;
    int rsub = lane >> 4;
    float s1[8] = {0.f,0.f,0.f,0.f,0.f,0.f,0.f,0.f};
    float s2[8] = {0.f,0.f,0.f,0.f,0.f,0.f,0.f,0.f};
    for (int r = blockIdx.x * 16 + wave * 4 + rsub; r < N; r += NSTAT * 16) {
        int4 u = B4[(size_t)r * 16 + c];
        float f[8] = { bflo(u.x), bfhi(u.x), bflo(u.y), bfhi(u.y),
                       bflo(u.z), bfhi(u.z), bflo(u.w), bfhi(u.w) };
#pragma unroll
        for (int j = 0; j < 8; ++j) { s1[j] += f[j]; s2[j] = fmaf(f[j], f[j], s2[j]); }
    }
#pragma unroll
    for (int j = 0; j < 8; ++j) {
        s1[j] += __shfl_xor(s1[j], 16, 64);
        s1[j] += __shfl_xor(s1[j], 32, 64);
        s2[j] += __shfl_xor(s2[j], 16, 64);
        s2[j] += __shfl_xor(s2[j], 32, 64);
    }
    __shared__ float ls1[4][128], ls2[4][128];
    if (rsub == 0) {
#pragma unroll
        for (int j = 0; j < 8; ++j) { ls1[wave][c * 8 + j] = s1[j]; ls2[wave][c * 8 + j] = s2[j]; }
    }
    __syncthreads();
    if (tid < 128) {
        P1[blockIdx.x * 128 + tid] = ls1[0][tid] + ls1[1][tid] + ls1[2][tid] + ls1[3][tid];
        P2[blockIdx.x * 128 + tid] = ls2[0][tid] + ls2[1][tid] + ls2[2][tid] + ls2[3][tid];
    }
}

// ---------- reduce partials + finalize BN scale/shift (one block per feature) ----------
__global__ __launch_bounds__(256) void k_bnfinal(const float* __restrict__ P1,
                          const float* __restrict__ P2,
                          const float* __restrict__ g, const float* __restrict__ be,
                          float* __restrict__ scale, float* __restrict__ shift,
                          float invN, int nPart) {
    int f = blockIdx.x, t = threadIdx.x;
    float s1 = 0.f, s2 = 0.f;
    for (int i = t; i < nPart; i += 256) {
        s1 += P1[(size_t)i * 128 + f];
        s2 += P2[(size_t)i * 128 + f];
    }
    __shared__ float l1[256], l2[256];
    l1[t] = s1; l2[t] = s2;
    __syncthreads();
    for (int off = 128; off > 0; off >>= 1) {
        if (t < off) { l1[t] += l1[t + off]; l2[t] += l2[t + off]; }
        __syncthreads();
    }
    if (t == 0) {
        float mu = l1[0] * invN;
        float var = l2[0] * invN - mu * mu;
        float sc = g[f] * rsqrtf(var + 1e-5f);
        scale[f] = sc;
        shift[f] = fmaf(-mu, sc, be[f]);
    }
}

// ---------- pool: LDS-staged accumulation, one global flush per block ----------
__global__ __launch_bounds__(256) void k_pool(const int4* __restrict__ B4,
                                              const float* __restrict__ scale,
                                              const float* __restrict__ shift,
                                              const int* __restrict__ batch, int N,
                                              int rpb, float* __restrict__ pooled,
                                              int* __restrict__ gcnt) {
    __shared__ float lp[64 * 128];
    __shared__ int lc[64];
    int tid = threadIdx.x;
    int r0 = blockIdx.x * rpb;
    if (r0 >= N) return;
    int r1 = min(r0 + rpb, N);
    int g0 = batch[r0];
    int g1 = batch[r1 - 1];
    // zero only the graph span this block touches (batch sorted -> small span)
    for (int i = g0 * 128 + tid; i < (g1 + 1) * 128; i += 256) lp[i] = 0.f;
    if (tid <= g1 - g0) lc[g0 + tid] = 0;
    __syncthreads();

    int c = tid & 15;
    int rh = tid >> 4;
    float sc[8], sh[8];
#pragma unroll
    for (int j = 0; j < 8; ++j) { sc[j] = scale[c * 8 + j]; sh[j] = shift[c * 8 + j]; }
    float acc[8] = {0.f,0.f,0.f,0.f,0.f,0.f,0.f,0.f};
    int cnt = 0;
    int cur = -1;
    for (int r = r0 + rh; r < r1; r += 16) {
        int g = batch[r];
        if (g != cur) {
            if (cur >= 0) {
#pragma unroll
                for (int j = 0; j < 8; ++j)
                    atomicAdd(&lp[cur * 128 + c * 8 + j], acc[j]);
                if (c == 0) atomicAdd(&lc[cur], cnt);
            }
#pragma unroll
            for (int j = 0; j < 8; ++j) acc[j] = 0.f;
            cnt = 0;
            cur = g;
        }
        int4 u = B4[(size_t)r * 16 + c];
        float f[8] = { bflo(u.x), bfhi(u.x), bflo(u.y), bfhi(u.y),
                       bflo(u.z), bfhi(u.z), bflo(u.w), bfhi(u.w) };
#pragma unroll
        for (int j = 0; j < 8; ++j) acc[j] += fmaxf(fmaf(f[j], sc[j], sh[j]), 0.f);
        ++cnt;
    }
    if (cur >= 0) {
#pragma unroll
        for (int j = 0; j < 8; ++j)
            atomicAdd(&lp[cur * 128 + c * 8 + j], acc[j]);
        if (c == 0) atomicAdd(&lc[cur], cnt);
    }
    __syncthreads();
    // single global flush of the touched span
    for (int i = g0 * 128 + tid; i < (g1 + 1) * 128; i += 256) {
        float v = lp[i];
        if (v != 0.f) atomicAdd(&pooled[i], v);
    }
    if (tid <= g1 - g0) {
        int v = lc[g0 + tid];
        if (v) atomicAdd(&gcnt[g0 + tid], v);
    }
}

// ---------- FC ----------
__global__ __launch_bounds__(256) void k_fc(const float* __restrict__ pooled,
                                            const int* __restrict__ gcnt,
                                            const float* __restrict__ Wfc,
                                            const float* __restrict__ bfc,
                                            float* __restrict__ out) {
    int idx = blockIdx.x * 256 + threadIdx.x;
    if (idx >= 64 * 32) return;
    int g = idx >> 5, o = idx & 31;
    float inv = 1.f / fmaxf((float)gcnt[g], 1.f);
    float acc = bfc[o];
    for (int k = 0; k < 128; ++k)
        acc = fmaf(pooled[g * 128 + k] * inv, Wfc[k * 32 + o], acc);
    out[idx] = acc;
}

extern "C" void kernel_launch(void* const* d_in, const int* in_sizes, int n_in,
                              void* d_out, int out_size, void* d_ws, size_t ws_size,
                              hipStream_t stream) {
    const float* x    = (const float*)d_in[0];
    const int*  eidx  = (const int*)d_in[1];
    const int*  batch = (const int*)d_in[2];
    const float* W0 = (const float*)d_in[3];
    const float* b0 = (const float*)d_in[4];
    const float* g0 = (const float*)d_in[5];
    const float* be0 = (const float*)d_in[6];
    const float* W1 = (const float*)d_in[7];
    const float* b1 = (const float*)d_in[8];
    const float* g1 = (const float*)d_in[9];
    const float* be1 = (const float*)d_in[10];
    const float* Wfc = (const float*)d_in[11];
    const float* bfc = (const float*)d_in[12];
    float* out = (float*)d_out;

    const int N = in_sizes[0] / 128;
    const int E = in_sizes[1] / 2;
    const int* esrc = eidx;
    const int* edst = eidx + E;
    const int NB = (N + 255) >> 8;               // buckets of 256 nodes (<=512)
    const size_t paddedE = (size_t)E + 7 * (size_t)N;

    // ---- workspace carve-up ----
    char* base = (char*)d_ws;
    size_t off = 0;
    auto take = [&](size_t bytes) -> char* {
        char* p = base + off;
        off = (off + bytes + 255) & ~(size_t)255;
        return p;
    };
    unsigned short* hA = (unsigned short*)take((size_t)N * 128 * 2); // bf16 h; aliased as rec
    int2* rec = (int2*)hA;                                           // bucket records (dead before gemm1)
    unsigned* B = (unsigned*)take((size_t)N * 64 * 4);               // bf16-packed agg buffer
    int2* csr   = (int2*)take(paddedE * 8);
    int2* rowdeg = (int2*)take((size_t)N * 8);
    int* deg    = (int*)take((size_t)N * 4);
    float* dinv = (float*)take((size_t)N * 4);
    int* counts = (int*)take((size_t)512 * NBLK * 4);                // 1 MB
    int* total  = (int*)take(512 * 4);
    int* bbase  = (int*)take(512 * 4);
    int* padsum = (int*)take(512 * 4);
    int* bucketBase = (int*)take(512 * 4);
    unsigned short* W0t = (unsigned short*)take(16384 * 2);
    unsigned short* W1t = (unsigned short*)take(16384 * 2);
    float* P1 = (float*)take((size_t)NSTAT * 128 * 4);
    float* P2 = (float*)take((size_t)NSTAT * 128 * 4);
    float* pooled = (float*)take(64 * 128 * 4);
    int*   gcnt   = (int*)take(64 * 4);
    float* scale1 = (float*)take(128 * 4);
    float* shift1 = (float*)take(128 * 4);
    float* scale2 = (float*)take(128 * 4);
    float* shift2 = (float*)take(128 * 4);
    (void)ws_size; (void)n_in; (void)out_size;

    // weight prep + zero pooled/gcnt (no memsets needed anywhere)
    k_wprep<<<16, 256, 0, stream>>>(W0, W1, W0t, W1t, pooled, gcnt);

    // ---- bucketed CSR build (deterministic, no global atomics) ----
    const int CH256 = (E + NBLK - 1) / NBLK;
    kb_count<<<NBLK, 256, 0, stream>>>(edst, E, NB, CH256, counts);
    kb_offsets<<<NB, NBLK, 0, stream>>>(counts, total);
    kb_base<<<1, 512, 0, stream>>>(total, NB, bbase);
    kb_scatter<<<NBLK, NBLK, 0, stream>>>(esrc, edst, E, NB, CH256, counts, bbase, rec);
    kb_deg<<<NB, 256, 0, stream>>>(rec, bbase, total, deg, dinv, padsum, N);
    kb_base<<<1, 512, 0, stream>>>(padsum, NB, bucketBase);
    kb_place<<<NB, 256, 0, stream>>>(rec, bbase, total, bucketBase, deg, dinv, csr, rowdeg, N);

    const int gGemm = (N + 63) / 64;
    const int gAgg  = (N + 3) / 4;
    const float invN = 1.0f / (float)N;

    // layer 1
    k_gemm<<<gGemm, 256, 0, stream>>>(x, W0t, scale1, shift1, hA, N, 0);
    k_agg<<<gAgg, 256, 0, stream>>>(hA, rowdeg, csr, dinv, b0, B, N);
    k_stats<<<NSTAT, 256, 0, stream>>>((const int4*)B, N, P1, P2);
    k_bnfinal<<<128, 256, 0, stream>>>(P1, P2, g0, be0, scale1, shift1, invN, NSTAT);

    // layer 2 (BN1+ReLU fused into GEMM2's staging)
    k_gemm<<<gGemm, 256, 0, stream>>>(B, W1t, scale1, shift1, hA, N, 1);
    k_agg<<<gAgg, 256, 0, stream>>>(hA, rowdeg, csr, dinv, b1, B, N);
    k_stats<<<NSTAT, 256, 0, stream>>>((const int4*)B, N, P1, P2);
    k_bnfinal<<<128, 256, 0, stream>>>(P1, P2, g1, be1, scale2, shift2, invN, NSTAT);

    // pool (BN2+ReLU+count fused, LDS-staged, wide grid) + FC
    const int gPool = 2048;
    const int rpb = (N + gPool - 1) / gPool;
    k_pool<<<gPool, 256, 0, stream>>>((const int4*)B, scale2, shift2, batch, N, rpb, pooled, gcnt);
    k_fc<<<8, 256, 0, stream>>>(pooled, gcnt, Wfc, bfc, out);
}

// Round 12
// 373.330 us; speedup vs baseline: 1.4219x; 1.0487x over previous
//
#include <hip/hip_runtime.h>

typedef short bf16x8 __attribute__((ext_vector_type(8)));
typedef float f32x4 __attribute__((ext_vector_type(4)));

#define NBLK 512   // scatter blocks (fixed for deterministic two-level offsets)
#define NSTAT 512  // stats partial blocks

// ---------- bf16 helpers ----------
__device__ __forceinline__ unsigned short f2bf(float f) {
    unsigned u = __float_as_uint(f);
    u += 0x7fffu + ((u >> 16) & 1u);   // round-to-nearest-even
    return (unsigned short)(u >> 16);
}
__device__ __forceinline__ float bflo(unsigned u) { return __uint_as_float(u << 16); }
__device__ __forceinline__ float bfhi(unsigned u) { return __uint_as_float(u & 0xffff0000u); }

// =================== bucketed CSR build (bucket = dst>>8; zero global atomics) ===================

__global__ __launch_bounds__(256) void kb_count(const int* __restrict__ dst, int E, int nb,
                                                int chunk, int* __restrict__ counts) {
    __shared__ int h[512];
    for (int i = threadIdx.x; i < 512; i += 256) h[i] = 0;
    __syncthreads();
    int e0 = blockIdx.x * chunk, e1 = min(e0 + chunk, E);
    for (int e = e0 + threadIdx.x; e < e1; e += 256) atomicAdd(&h[dst[e] >> 8], 1);
    __syncthreads();
    for (int b = threadIdx.x; b < nb; b += 256) counts[b * NBLK + blockIdx.x] = h[b];
}

__global__ __launch_bounds__(NBLK) void kb_offsets(int* __restrict__ counts,
                                                   int* __restrict__ total) {
    __shared__ int s[NBLK];
    int b = blockIdx.x, t = threadIdx.x;
    int v = counts[b * NBLK + t];
    s[t] = v; __syncthreads();
    for (int off = 1; off < NBLK; off <<= 1) {
        int x = (t >= off) ? s[t - off] : 0;
        __syncthreads();
        s[t] += x;
        __syncthreads();
    }
    counts[b * NBLK + t] = s[t] - v;          // exclusive
    if (t == NBLK - 1) total[b] = s[t];
}

// generic 512-entry exclusive scan (bucket totals AND bucket pad-sums)
__global__ __launch_bounds__(512) void kb_base(const int* __restrict__ in, int nb,
                                               int* __restrict__ outb) {
    __shared__ int s[512];
    int t = threadIdx.x;
    int v = (t < nb) ? in[t] : 0;
    s[t] = v; __syncthreads();
    for (int off = 1; off < 512; off <<= 1) {
        int x = (t >= off) ? s[t - off] : 0;
        __syncthreads();
        s[t] += x;
        __syncthreads();
    }
    if (t < nb) outb[t] = s[t] - v;
}

__global__ __launch_bounds__(NBLK) void kb_scatter(const int* __restrict__ src,
                                                   const int* __restrict__ dst, int E, int nb,
                                                   int chunk,
                                                   const int* __restrict__ counts,
                                                   const int* __restrict__ bbase,
                                                   int2* __restrict__ rec) {
    __shared__ int cur[512];
    int t = threadIdx.x;
    if (t < nb) cur[t] = bbase[t] + counts[t * NBLK + blockIdx.x];
    __syncthreads();
    int e0 = blockIdx.x * chunk, e1 = min(e0 + chunk, E);
    for (int e = e0 + t; e < e1; e += NBLK) {
        int s = src[e], d = dst[e];
        int pos = atomicAdd(&cur[d >> 8], 1);
        rec[pos] = make_int2(s, d);
    }
}

// per-bucket degree count via LDS (+ fused dinv, + bucket padded-deg sum)
__global__ __launch_bounds__(256) void kb_deg(const int2* __restrict__ rec,
                                              const int* __restrict__ bbase,
                                              const int* __restrict__ total,
                                              int* __restrict__ deg,
                                              float* __restrict__ dinv,
                                              int* __restrict__ padsum, int N) {
    __shared__ int dc[256];
    int b = blockIdx.x, t = threadIdx.x;
    dc[t] = 0; __syncthreads();
    int r0 = bbase[b], r1 = r0 + total[b];
    for (int i = r0 + t; i < r1; i += 256) atomicAdd(&dc[rec[i].y & 255], 1);
    __syncthreads();
    int gn = b * 256 + t;
    int d = dc[t];
    int pd = (gn < N) ? ((d + 7) & ~7) : 0;
    if (gn < N) {
        deg[gn] = d;
        dinv[gn] = rsqrtf((float)(d + 1));
    }
    __syncthreads();
    dc[t] = pd; __syncthreads();
    for (int off = 128; off > 0; off >>= 1) {
        if (t < off) dc[t] += dc[t + off];
        __syncthreads();
    }
    if (t == 0) padsum[b] = dc[0];
}

// per-bucket CSR placement: intra-bucket scan -> rowdeg{start,pd}, LDS cursors, pad writes
__global__ __launch_bounds__(256) void kb_place(const int2* __restrict__ rec,
                                                const int* __restrict__ bbase,
                                                const int* __restrict__ total,
                                                const int* __restrict__ bucketBase,
                                                const int* __restrict__ deg,
                                                const float* __restrict__ dinv,
                                                int2* __restrict__ csr,
                                                int2* __restrict__ rowdeg, int N) {
    __shared__ int sc[256];
    __shared__ int cur[256];
    int b = blockIdx.x, t = threadIdx.x;
    int gn = b * 256 + t;
    int d = (gn < N) ? deg[gn] : 0;
    int pd = (d + 7) & ~7;
    sc[t] = pd; __syncthreads();
    for (int off = 1; off < 256; off <<= 1) {
        int x = (t >= off) ? sc[t - off] : 0;
        __syncthreads();
        sc[t] += x;
        __syncthreads();
    }
    int rp = bucketBase[b] + sc[t] - pd;
    if (gn < N) rowdeg[gn] = make_int2(rp, pd);
    cur[t] = rp;
    __syncthreads();
    int r0 = bbase[b], r1 = r0 + total[b];
    for (int i = r0 + t; i < r1; i += 256) {
        int2 rc = rec[i];
        int pos = atomicAdd(&cur[rc.y & 255], 1);
        float w = dinv[rc.x] * dinv[rc.y];
        csr[pos] = make_int2(rc.x, __float_as_int(w));
    }
    __syncthreads();
    if (gn < N) {
        int end = cur[t];                       // start + deg
        int pe = rp + pd;
        for (int i = end; i < pe; ++i) csr[i] = make_int2(0, 0);  // {src=0, w=0}
    }
}

// =================== W prep (both weights) + zero pooled/gcnt ===================
__global__ __launch_bounds__(256) void k_wprep(const float* __restrict__ W0,
                                               const float* __restrict__ W1,
                                               unsigned short* __restrict__ W0t,
                                               unsigned short* __restrict__ W1t,
                                               float* __restrict__ pooled,
                                               int* __restrict__ gcnt) {
    int tt = blockIdx.x * 256 + threadIdx.x;   // 4096 = 2 * 32 frags * 64 lanes
    pooled[tt] = 0.f;
    pooled[tt + 4096] = 0.f;
    if (tt < 64) gcnt[tt] = 0;
    const float* W = (tt < 2048) ? W0 : W1;
    unsigned short* Wt = (tt < 2048) ? W0t : W1t;
    int t = tt & 2047;
    int f = t >> 6, lane = t & 63;
    int kc = f >> 3, nt = f & 7;
    int kbase = kc * 32 + (lane >> 4) * 8;
    int n = nt * 16 + (lane & 15);
    unsigned short t8[8];
#pragma unroll
    for (int j = 0; j < 8; ++j) t8[j] = f2bf(W[(size_t)(kbase + j) * 128 + n]);
    unsigned short* o = &Wt[(size_t)t * 8];
    *(ushort4*)&o[0] = *(ushort4*)&t8[0];
    *(ushort4*)&o[4] = *(ushort4*)&t8[4];
}

// =================== MFMA GEMM: Hout(bf16) = act(X) @ W ===================
__global__ __launch_bounds__(256) void k_gemm(const void* __restrict__ Xv,
                                              const unsigned short* __restrict__ Wt,
                                              const float* __restrict__ scale,
                                              const float* __restrict__ shift,
                                              unsigned short* __restrict__ Hout,
                                              int N, int xbf16) {
    __shared__ unsigned short sX[64 * 136];
    const int tid = threadIdx.x;
    const int rowBase = blockIdx.x * 64;

    if (!xbf16) {
        const float* X = (const float*)Xv;
#pragma unroll
        for (int i = 0; i < 8; ++i) {
            int f4 = tid + 256 * i;
            int r = f4 >> 5; int k4 = (f4 & 31) * 4;
            int gr = rowBase + r;
            float4 v = make_float4(0.f, 0.f, 0.f, 0.f);
            if (gr < N) v = *(const float4*)&X[(size_t)gr * 128 + k4];
            ushort4 p;
            p.x = f2bf(v.x); p.y = f2bf(v.y); p.z = f2bf(v.z); p.w = f2bf(v.w);
            *(ushort4*)&sX[r * 136 + k4] = p;
        }
    } else {
        const int4* X = (const int4*)Xv;
#pragma unroll
        for (int i = 0; i < 4; ++i) {
            int f8 = tid + 256 * i;
            int r = f8 >> 4; int k8 = (f8 & 15) * 8;
            int gr = rowBase + r;
            int4 u = make_int4(0, 0, 0, 0);
            if (gr < N) u = X[(size_t)gr * 16 + (f8 & 15)];
            float fv[8] = { bflo(u.x), bfhi(u.x), bflo(u.y), bfhi(u.y),
                            bflo(u.z), bfhi(u.z), bflo(u.w), bfhi(u.w) };
            unsigned short t8[8];
#pragma unroll
            for (int j = 0; j < 8; ++j)
                t8[j] = f2bf(fmaxf(fmaf(fv[j], scale[k8 + j], shift[k8 + j]), 0.f));
            *(ushort4*)&sX[r * 136 + k8]     = *(ushort4*)&t8[0];
            *(ushort4*)&sX[r * 136 + k8 + 4] = *(ushort4*)&t8[4];
        }
    }
    __syncthreads();

    const int lane = tid & 63, wave = tid >> 6;
    const int m = lane & 15, q = lane >> 4;
    const int rowOff = (wave * 16 + m) * 136 + q * 8;
    f32x4 acc[8];
#pragma unroll
    for (int nt = 0; nt < 8; ++nt) acc[nt] = (f32x4){0.f, 0.f, 0.f, 0.f};
    const bf16x8* WtF = (const bf16x8*)Wt;
#pragma unroll
    for (int kc = 0; kc < 4; ++kc) {
        bf16x8 xb = *(const bf16x8*)&sX[rowOff + kc * 32];
#pragma unroll
        for (int nt = 0; nt < 8; ++nt) {
            bf16x8 wa = WtF[(kc * 8 + nt) * 64 + lane];
            acc[nt] = __builtin_amdgcn_mfma_f32_16x16x32_bf16(wa, xb, acc[nt], 0, 0, 0);
        }
    }
    int grow = rowBase + wave * 16 + m;
    if (grow < N) {
#pragma unroll
        for (int nt = 0; nt < 8; ++nt) {
            ushort4 p;
            p.x = f2bf(acc[nt][0]); p.y = f2bf(acc[nt][1]);
            p.z = f2bf(acc[nt][2]); p.w = f2bf(acc[nt][3]);
            *(ushort4*)&Hout[(size_t)grow * 128 + nt * 16 + q * 4] = p;
        }
    }
}

// =================== aggregation: 1 node/wave, pad-8, 16-deep unroll ===================
__global__ __launch_bounds__(256) void k_agg(const unsigned short* __restrict__ H,
                                             const int2* __restrict__ rowdeg,
                                             const int2* __restrict__ csr,
                                             const float* __restrict__ dinv,
                                             const float* __restrict__ bias,
                                             unsigned* __restrict__ out, int N) {
    int wave = threadIdx.x >> 6;
    int lane = threadIdx.x & 63;
    int node = blockIdx.x * 4 + wave;
    if (node >= N) return;
    const unsigned* Hu = (const unsigned*)H;
    int2 rd = rowdeg[node];
    int start = rd.x, pd = rd.y;
    float a0 = 0.f, a1 = 0.f;
    const int4* cp = (const int4*)(csr + start);
    int j = 0;
    for (; j + 16 <= pd; j += 16) {
        int4 q0 = cp[0], q1 = cp[1], q2 = cp[2], q3 = cp[3];
        int4 q4 = cp[4], q5 = cp[5], q6 = cp[6], q7 = cp[7];
        cp += 8;
        unsigned u0 = Hu[(size_t)q0.x * 64 + lane];
        unsigned u1 = Hu[(size_t)q0.z * 64 + lane];
        unsigned u2 = Hu[(size_t)q1.x * 64 + lane];
        unsigned u3 = Hu[(size_t)q1.z * 64 + lane];
        unsigned u4 = Hu[(size_t)q2.x * 64 + lane];
        unsigned u5 = Hu[(size_t)q2.z * 64 + lane];
        unsigned u6 = Hu[(size_t)q3.x * 64 + lane];
        unsigned u7 = Hu[(size_t)q3.z * 64 + lane];
        unsigned u8 = Hu[(size_t)q4.x * 64 + lane];
        unsigned u9 = Hu[(size_t)q4.z * 64 + lane];
        unsigned uA = Hu[(size_t)q5.x * 64 + lane];
        unsigned uB = Hu[(size_t)q5.z * 64 + lane];
        unsigned uC = Hu[(size_t)q6.x * 64 + lane];
        unsigned uD = Hu[(size_t)q6.z * 64 + lane];
        unsigned uE = Hu[(size_t)q7.x * 64 + lane];
        unsigned uF = Hu[(size_t)q7.z * 64 + lane];
        float w0 = __int_as_float(q0.y), w1 = __int_as_float(q0.w);
        float w2 = __int_as_float(q1.y), w3 = __int_as_float(q1.w);
        float w4 = __int_as_float(q2.y), w5 = __int_as_float(q2.w);
        float w6 = __int_as_float(q3.y), w7 = __int_as_float(q3.w);
        float w8 = __int_as_float(q4.y), w9 = __int_as_float(q4.w);
        float wA = __int_as_float(q5.y), wB = __int_as_float(q5.w);
        float wC = __int_as_float(q6.y), wD = __int_as_float(q6.w);
        float wE = __int_as_float(q7.y), wF = __int_as_float(q7.w);
        a0 = fmaf(w0, bflo(u0), a0); a1 = fmaf(w0, bfhi(u0), a1);
        a0 = fmaf(w1, bflo(u1), a0); a1 = fmaf(w1, bfhi(u1), a1);
        a0 = fmaf(w2, bflo(u2), a0); a1 = fmaf(w2, bfhi(u2), a1);
        a0 = fmaf(w3, bflo(u3), a0); a1 = fmaf(w3, bfhi(u3), a1);
        a0 = fmaf(w4, bflo(u4), a0); a1 = fmaf(w4, bfhi(u4), a1);
        a0 = fmaf(w5, bflo(u5), a0); a1 = fmaf(w5, bfhi(u5), a1);
        a0 = fmaf(w6, bflo(u6), a0); a1 = fmaf(w6, bfhi(u6), a1);
        a0 = fmaf(w7, bflo(u7), a0); a1 = fmaf(w7, bfhi(u7), a1);
        a0 = fmaf(w8, bflo(u8), a0); a1 = fmaf(w8, bfhi(u8), a1);
        a0 = fmaf(w9, bflo(u9), a0); a1 = fmaf(w9, bfhi(u9), a1);
        a0 = fmaf(wA, bflo(uA), a0); a1 = fmaf(wA, bfhi(uA), a1);
        a0 = fmaf(wB, bflo(uB), a0); a1 = fmaf(wB, bfhi(uB), a1);
        a0 = fmaf(wC, bflo(uC), a0); a1 = fmaf(wC, bfhi(uC), a1);
        a0 = fmaf(wD, bflo(uD), a0); a1 = fmaf(wD, bfhi(uD), a1);
        a0 = fmaf(wE, bflo(uE), a0); a1 = fmaf(wE, bfhi(uE), a1);
        a0 = fmaf(wF, bflo(uF), a0); a1 = fmaf(wF, bfhi(uF), a1);
    }
    if (j < pd) {   // remaining group of 8
        int4 q0 = cp[0], q1 = cp[1], q2 = cp[2], q3 = cp[3];
        unsigned u0 = Hu[(size_t)q0.x * 64 + lane];
        unsigned u1 = Hu[(size_t)q0.z * 64 + lane];
        unsigned u2 = Hu[(size_t)q1.x * 64 + lane];
        unsigned u3 = Hu[(size_t)q1.z * 64 + lane];
        unsigned u4 = Hu[(size_t)q2.x * 64 + lane];
        unsigned u5 = Hu[(size_t)q2.z * 64 + lane];
        unsigned u6 = Hu[(size_t)q3.x * 64 + lane];
        unsigned u7 = Hu[(size_t)q3.z * 64 + lane];
        float w0 = __int_as_float(q0.y), w1 = __int_as_float(q0.w);
        float w2 = __int_as_float(q1.y), w3 = __int_as_float(q1.w);
        float w4 = __int_as_float(q2.y), w5 = __int_as_float(q2.w);
        float w6 = __int_as_float(q3.y), w7 = __int_as_float(q3.w);
        a0 = fmaf(w0, bflo(u0), a0); a1 = fmaf(w0, bfhi(u0), a1);
        a0 = fmaf(w1, bflo(u1), a0); a1 = fmaf(w1, bfhi(u1), a1);
        a0 = fmaf(w2, bflo(u2), a0); a1 = fmaf(w2, bfhi(u2), a1);
        a0 = fmaf(w3, bflo(u3), a0); a1 = fmaf(w3, bfhi(u3), a1);
        a0 = fmaf(w4, bflo(u4), a0); a1 = fmaf(w4, bfhi(u4), a1);
        a0 = fmaf(w5, bflo(u5), a0); a1 = fmaf(w5, bfhi(u5), a1);
        a0 = fmaf(w6, bflo(u6), a0); a1 = fmaf(w6, bfhi(u6), a1);
        a0 = fmaf(w7, bflo(u7), a0); a1 = fmaf(w7, bfhi(u7), a1);
    }
    { // self loop
        float dn = dinv[node];
        float w = dn * dn;
        unsigned u = Hu[(size_t)node * 64 + lane];
        a0 = fmaf(w, bflo(u), a0);
        a1 = fmaf(w, bfhi(u), a1);
    }
    float2 bv = ((const float2*)bias)[lane];
    a0 += bv.x; a1 += bv.y;
    out[(size_t)node * 64 + lane] = (unsigned)f2bf(a0) | ((unsigned)f2bf(a1) << 16);
}

// ---------- BN column stats: int4 loads, shuffle-reduce, per-block partials ----------
__global__ __launch_bounds__(256) void k_stats(const int4* __restrict__ B4, int N,
                                               float* __restrict__ P1,
                                               float* __restrict__ P2) {
    int tid = threadIdx.x;
    int lane = tid & 63, wave = tid >> 6;
    int c = lane & 15;
    int rsub = lane >> 4;
    float s1[8] = {0.f,0.f,0.f,0.f,0.f,0.f,0.f,0.f};
    float s2[8] = {0.f,0.f,0.f,0.f,0.f,0.f,0.f,0.f};
    for (int r = blockIdx.x * 16 + wave * 4 + rsub; r < N; r += NSTAT * 16) {
        int4 u = B4[(size_t)r * 16 + c];
        float f[8] = { bflo(u.x), bfhi(u.x), bflo(u.y), bfhi(u.y),
                       bflo(u.z), bfhi(u.z), bflo(u.w), bfhi(u.w) };
#pragma unroll
        for (int j = 0; j < 8; ++j) { s1[j] += f[j]; s2[j] = fmaf(f[j], f[j], s2[j]); }
    }
#pragma unroll
    for (int j = 0; j < 8; ++j) {
        s1[j] += __shfl_xor(s1[j], 16, 64);
        s1[j] += __shfl_xor(s1[j], 32, 64);
        s2[j] += __shfl_xor(s2[j], 16, 64);
        s2[j] += __shfl_xor(s2[j], 32, 64);
    }
    __shared__ float ls1[4][128], ls2[4][128];
    if (rsub == 0) {
#pragma unroll
        for (int j = 0; j < 8; ++j) { ls1[wave][c * 8 + j] = s1[j]; ls2[wave][c * 8 + j] = s2[j]; }
    }
    __syncthreads();
    if (tid < 128) {
        P1[blockIdx.x * 128 + tid] = ls1[0][tid] + ls1[1][tid] + ls1[2][tid] + ls1[3][tid];
        P2[blockIdx.x * 128 + tid] = ls2[0][tid] + ls2[1][tid] + ls2[2][tid] + ls2[3][tid];
    }
}

// ---------- reduce partials + finalize BN scale/shift (one block per feature) ----------
__global__ __launch_bounds__(256) void k_bnfinal(const float* __restrict__ P1,
                          const float* __restrict__ P2,
                          const float* __restrict__ g, const float* __restrict__ be,
                          float* __restrict__ scale, float* __restrict__ shift,
                          float invN, int nPart) {
    int f = blockIdx.x, t = threadIdx.x;
    float s1 = 0.f, s2 = 0.f;
    for (int i = t; i < nPart; i += 256) {
        s1 += P1[(size_t)i * 128 + f];
        s2 += P2[(size_t)i * 128 + f];
    }
    __shared__ float l1[256], l2[256];
    l1[t] = s1; l2[t] = s2;
    __syncthreads();
    for (int off = 128; off > 0; off >>= 1) {
        if (t < off) { l1[t] += l1[t + off]; l2[t] += l2[t + off]; }
        __syncthreads();
    }
    if (t == 0) {
        float mu = l1[0] * invN;
        float var = l2[0] * invN - mu * mu;
        float sc = g[f] * rsqrtf(var + 1e-5f);
        scale[f] = sc;
        shift[f] = fmaf(-mu, sc, be[f]);
    }
}

// ---------- pool: LDS-staged accumulation, one global flush per block ----------
__global__ __launch_bounds__(256) void k_pool(const int4* __restrict__ B4,
                                              const float* __restrict__ scale,
                                              const float* __restrict__ shift,
                                              const int* __restrict__ batch, int N,
                                              int rpb, float* __restrict__ pooled,
                                              int* __restrict__ gcnt) {
    __shared__ float lp[64 * 128];
    __shared__ int lc[64];
    int tid = threadIdx.x;
    int r0 = blockIdx.x * rpb;
    if (r0 >= N) return;
    int r1 = min(r0 + rpb, N);
    int g0 = batch[r0];
    int g1 = batch[r1 - 1];
    // zero only the graph span this block touches (batch sorted -> small span)
    for (int i = g0 * 128 + tid; i < (g1 + 1) * 128; i += 256) lp[i] = 0.f;
    if (tid <= g1 - g0) lc[g0 + tid] = 0;
    __syncthreads();

    int c = tid & 15;
    int rh = tid >> 4;
    float sc[8], sh[8];
#pragma unroll
    for (int j = 0; j < 8; ++j) { sc[j] = scale[c * 8 + j]; sh[j] = shift[c * 8 + j]; }
    float acc[8] = {0.f,0.f,0.f,0.f,0.f,0.f,0.f,0.f};
    int cnt = 0;
    int cur = -1;
    for (int r = r0 + rh; r < r1; r += 16) {
        int g = batch[r];
        if (g != cur) {
            if (cur >= 0) {
#pragma unroll
                for (int j = 0; j < 8; ++j)
                    atomicAdd(&lp[cur * 128 + c * 8 + j], acc[j]);
                if (c == 0) atomicAdd(&lc[cur], cnt);
            }
#pragma unroll
            for (int j = 0; j < 8; ++j) acc[j] = 0.f;
            cnt = 0;
            cur = g;
        }
        int4 u = B4[(size_t)r * 16 + c];
        float f[8] = { bflo(u.x), bfhi(u.x), bflo(u.y), bfhi(u.y),
                       bflo(u.z), bfhi(u.z), bflo(u.w), bfhi(u.w) };
#pragma unroll
        for (int j = 0; j < 8; ++j) acc[j] += fmaxf(fmaf(f[j], sc[j], sh[j]), 0.f);
        ++cnt;
    }
    if (cur >= 0) {
#pragma unroll
        for (int j = 0; j < 8; ++j)
            atomicAdd(&lp[cur * 128 + c * 8 + j], acc[j]);
        if (c == 0) atomicAdd(&lc[cur], cnt);
    }
    __syncthreads();
    // single global flush of the touched span
    for (int i = g0 * 128 + tid; i < (g1 + 1) * 128; i += 256) {
        float v = lp[i];
        if (v != 0.f) atomicAdd(&pooled[i], v);
    }
    if (tid <= g1 - g0) {
        int v = lc[g0 + tid];
        if (v) atomicAdd(&gcnt[g0 + tid], v);
    }
}

// ---------- FC ----------
__global__ __launch_bounds__(256) void k_fc(const float* __restrict__ pooled,
                                            const int* __restrict__ gcnt,
                                            const float* __restrict__ Wfc,
                                            const float* __restrict__ bfc,
                                            float* __restrict__ out) {
    int idx = blockIdx.x * 256 + threadIdx.x;
    if (idx >= 64 * 32) return;
    int g = idx >> 5, o = idx & 31;
    float inv = 1.f / fmaxf((float)gcnt[g], 1.f);
    float acc = bfc[o];
    for (int k = 0; k < 128; ++k)
        acc = fmaf(pooled[g * 128 + k] * inv, Wfc[k * 32 + o], acc);
    out[idx] = acc;
}

extern "C" void kernel_launch(void* const* d_in, const int* in_sizes, int n_in,
                              void* d_out, int out_size, void* d_ws, size_t ws_size,
                              hipStream_t stream) {
    const float* x    = (const float*)d_in[0];
    const int*  eidx  = (const int*)d_in[1];
    const int*  batch = (const int*)d_in[2];
    const float* W0 = (const float*)d_in[3];
    const float* b0 = (const float*)d_in[4];
    const float* g0 = (const float*)d_in[5];
    const float* be0 = (const float*)d_in[6];
    const float* W1 = (const float*)d_in[7];
    const float* b1 = (const float*)d_in[8];
    const float* g1 = (const float*)d_in[9];
    const float* be1 = (const float*)d_in[10];
    const float* Wfc = (const float*)d_in[11];
    const float* bfc = (const float*)d_in[12];
    float* out = (float*)d_out;

    const int N = in_sizes[0] / 128;
    const int E = in_sizes[1] / 2;
    const int* esrc = eidx;
    const int* edst = eidx + E;
    const int NB = (N + 255) >> 8;               // buckets of 256 nodes (<=512)
    const size_t paddedE = (size_t)E + 7 * (size_t)N;

    // ---- workspace carve-up ----
    char* base = (char*)d_ws;
    size_t off = 0;
    auto take = [&](size_t bytes) -> char* {
        char* p = base + off;
        off = (off + bytes + 255) & ~(size_t)255;
        return p;
    };
    unsigned short* hA = (unsigned short*)take((size_t)N * 128 * 2); // bf16 h; aliased as rec
    int2* rec = (int2*)hA;                                           // bucket records (dead before gemm1)
    unsigned* B = (unsigned*)take((size_t)N * 64 * 4);               // bf16-packed agg buffer
    int2* csr   = (int2*)take(paddedE * 8);
    int2* rowdeg = (int2*)take((size_t)N * 8);
    int* deg    = (int*)take((size_t)N * 4);
    float* dinv = (float*)take((size_t)N * 4);
    int* counts = (int*)take((size_t)512 * NBLK * 4);                // 1 MB
    int* total  = (int*)take(512 * 4);
    int* bbase  = (int*)take(512 * 4);
    int* padsum = (int*)take(512 * 4);
    int* bucketBase = (int*)take(512 * 4);
    unsigned short* W0t = (unsigned short*)take(16384 * 2);
    unsigned short* W1t = (unsigned short*)take(16384 * 2);
    float* P1 = (float*)take((size_t)NSTAT * 128 * 4);
    float* P2 = (float*)take((size_t)NSTAT * 128 * 4);
    float* pooled = (float*)take(64 * 128 * 4);
    int*   gcnt   = (int*)take(64 * 4);
    float* scale1 = (float*)take(128 * 4);
    float* shift1 = (float*)take(128 * 4);
    float* scale2 = (float*)take(128 * 4);
    float* shift2 = (float*)take(128 * 4);
    (void)ws_size; (void)n_in; (void)out_size;

    // weight prep + zero pooled/gcnt (no memsets needed anywhere)
    k_wprep<<<16, 256, 0, stream>>>(W0, W1, W0t, W1t, pooled, gcnt);

    // ---- bucketed CSR build (deterministic, no global atomics) ----
    const int CH256 = (E + NBLK - 1) / NBLK;
    kb_count<<<NBLK, 256, 0, stream>>>(edst, E, NB, CH256, counts);
    kb_offsets<<<NB, NBLK, 0, stream>>>(counts, total);
    kb_base<<<1, 512, 0, stream>>>(total, NB, bbase);
    kb_scatter<<<NBLK, NBLK, 0, stream>>>(esrc, edst, E, NB, CH256, counts, bbase, rec);
    kb_deg<<<NB, 256, 0, stream>>>(rec, bbase, total, deg, dinv, padsum, N);
    kb_base<<<1, 512, 0, stream>>>(padsum, NB, bucketBase);
    kb_place<<<NB, 256, 0, stream>>>(rec, bbase, total, bucketBase, deg, dinv, csr, rowdeg, N);

    const int gGemm = (N + 63) / 64;
    const int gAgg  = (N + 3) / 4;
    const float invN = 1.0f / (float)N;

    // layer 1
    k_gemm<<<gGemm, 256, 0, stream>>>(x, W0t, scale1, shift1, hA, N, 0);
    k_agg<<<gAgg, 256, 0, stream>>>(hA, rowdeg, csr, dinv, b0, B, N);
    k_stats<<<NSTAT, 256, 0, stream>>>((const int4*)B, N, P1, P2);
    k_bnfinal<<<128, 256, 0, stream>>>(P1, P2, g0, be0, scale1, shift1, invN, NSTAT);

    // layer 2 (BN1+ReLU fused into GEMM2's staging)
    k_gemm<<<gGemm, 256, 0, stream>>>(B, W1t, scale1, shift1, hA, N, 1);
    k_agg<<<gAgg, 256, 0, stream>>>(hA, rowdeg, csr, dinv, b1, B, N);
    k_stats<<<NSTAT, 256, 0, stream>>>((const int4*)B, N, P1, P2);
    k_bnfinal<<<128, 256, 0, stream>>>(P1, P2, g1, be1, scale2, shift2, invN, NSTAT);

    // pool (BN2+ReLU+count fused, LDS-staged) + FC
    const int rpb = (N + 511) / 512;
    k_pool<<<(N + rpb - 1) / rpb, 256, 0, stream>>>((const int4*)B, scale2, shift2, batch, N, rpb, pooled, gcnt);
    k_fc<<<8, 256, 0, stream>>>(pooled, gcnt, Wfc, bfc, out);
}